// Round 2
// baseline (3768.497 us; speedup 1.0000x reference)
//
#include <hip/hip_runtime.h>
#include <hip/hip_bf16.h>
#include <stdint.h>

#define NN   100000   // nodes per type
#define EE   600000   // edges per type
#define HH   128      // hidden
#define OUTC 64       // out channels

typedef __attribute__((ext_vector_type(8))) short bf16x8;   // 8 bf16 in 4 VGPRs
typedef __attribute__((ext_vector_type(4))) float f32x4;

__device__ __forceinline__ float bfbits2f(unsigned short b) {
    union { unsigned u; float f; } v; v.u = ((unsigned)b) << 16; return v.f;
}
__device__ __forceinline__ unsigned short f2bfbits(float f) {
    union { float f; unsigned u; } v; v.f = f;
    unsigned r = v.u + 0x7fffu + ((v.u >> 16) & 1u);   // RNE
    return (unsigned short)(r >> 16);
}

// ---------------------------------------------------------------------------
// fp32 -> bf16 bulk convert (weights; once per launch)
// ---------------------------------------------------------------------------
__global__ __launch_bounds__(256) void cvt_f32_bf16(
    const float* __restrict__ in, unsigned short* __restrict__ out, int n)
{
    int i = blockIdx.x * 256 + threadIdx.x;
    if (i < n) out[i] = f2bfbits(in[i]);
}

// ---------------------------------------------------------------------------
// Scatter-add: one wave per edge; lane handles features [2*lane, 2*lane+1].
// SRCF32: gather from fp32 features; else from bf16 intermediate.
// agg fp32 accumulators + fp32 degree counts via HW global_atomic_add_f32.
// ---------------------------------------------------------------------------
template<bool SRCF32>
__global__ __launch_bounds__(256) void scatter_edges(
    const int* __restrict__ ei,     // [2*EE]: src row then dst row
    const void* __restrict__ xsrc_, // [NN*HH] fp32 or bf16 bits
    float* __restrict__ agg,        // [NN*HH] fp32 (pre-zeroed)
    float* __restrict__ deg)        // [NN] fp32 (pre-zeroed)
{
    int gid  = blockIdx.x * 256 + threadIdx.x;
    int e    = gid >> 6;
    int lane = threadIdx.x & 63;
    if (e >= EE) return;
    int src = ei[e];
    int dst = ei[EE + e];
    float lo, hi;
    if (SRCF32) {
        const float2 v = ((const float2*)((const float*)xsrc_ + (size_t)src * HH))[lane];
        lo = v.x; hi = v.y;
    } else {
        unsigned v = ((const unsigned*)((const unsigned short*)xsrc_ + (size_t)src * HH))[lane];
        lo = bfbits2f((unsigned short)(v & 0xffffu));
        hi = bfbits2f((unsigned short)(v >> 16));
    }
    float* a = agg + (size_t)dst * HH + lane * 2;
    unsafeAtomicAdd(a,     lo);
    unsafeAtomicAdd(a + 1, hi);
    if (lane == 0) unsafeAtomicAdd(deg + dst, 1.0f);
}

// ---------------------------------------------------------------------------
// SAGE GEMM + fused LN/ReLU/residual epilogue.
//   C = aggA/degA @ WlA^T + X @ WrA^T + blA   (+ aggB/degB @ WlB^T + X @ WrB^T + blB)
//   out = relu(LN(scale*C; g,b)) + X          (scale=0.5 when twoAgg)
// One wave = 16 rows x 128 cols; block = 4 waves = 64 rows.
// Weights pre-converted bf16. XF32: root/residual features fp32 (layer-1 roots)
// else bf16 (layer-2 root s1). Output stored bf16 (intermediate).
// ---------------------------------------------------------------------------
template<bool XF32>
__global__ __launch_bounds__(256) void sage_gemm(
    const float* __restrict__ aggA, const float* __restrict__ degA,
    const unsigned short* __restrict__ WlA, const float* __restrict__ blA,
    const float* __restrict__ aggB, const float* __restrict__ degB,
    const unsigned short* __restrict__ WlB, const float* __restrict__ blB,
    const void* __restrict__ X,       // root features = residual source
    const unsigned short* __restrict__ WrA, const unsigned short* __restrict__ WrB,
    const float* __restrict__ g, const float* __restrict__ bt,
    unsigned short* __restrict__ out, int twoAgg)
{
    const int lane = threadIdx.x & 63;
    const int wid  = threadIdx.x >> 6;
    const int m    = lane & 15;     // A-row within tile / C-col within ct tile
    const int q    = lane >> 4;     // quad
    const int row0 = blockIdx.x * 64 + wid * 16;

    int arow = row0 + m;
    if (arow >= NN) arow = NN - 1;          // clamp loads; stores guarded

    const float invA = 1.0f / fmaxf(degA[arow], 1.0f);
    const float invB = twoAgg ? (1.0f / fmaxf(degB[arow], 1.0f)) : 0.0f;

    f32x4 acc[8];
    for (int ct = 0; ct < 8; ++ct) acc[ct] = (f32x4){0.f, 0.f, 0.f, 0.f};

    for (int ks = 0; ks < 4; ++ks) {
        const int k0 = ks * 32 + q * 8;
        // root fragment -> bf16
        bf16x8 aR;
        if (XF32) {
            f32x4 r0 = *(const f32x4*)((const float*)X + (size_t)arow * HH + k0);
            f32x4 r1 = *(const f32x4*)((const float*)X + (size_t)arow * HH + k0 + 4);
            aR[0] = (short)f2bfbits(r0[0]); aR[1] = (short)f2bfbits(r0[1]);
            aR[2] = (short)f2bfbits(r0[2]); aR[3] = (short)f2bfbits(r0[3]);
            aR[4] = (short)f2bfbits(r1[0]); aR[5] = (short)f2bfbits(r1[1]);
            aR[6] = (short)f2bfbits(r1[2]); aR[7] = (short)f2bfbits(r1[3]);
        } else {
            aR = *(const bf16x8*)((const unsigned short*)X + (size_t)arow * HH + k0);
        }
        // aggA fragment: fp32 load, deg-normalize, round to bf16
        f32x4 a0 = *(const f32x4*)(aggA + (size_t)arow * HH + k0);
        f32x4 a1 = *(const f32x4*)(aggA + (size_t)arow * HH + k0 + 4);
        bf16x8 aA;
        aA[0] = (short)f2bfbits(a0[0] * invA); aA[1] = (short)f2bfbits(a0[1] * invA);
        aA[2] = (short)f2bfbits(a0[2] * invA); aA[3] = (short)f2bfbits(a0[3] * invA);
        aA[4] = (short)f2bfbits(a1[0] * invA); aA[5] = (short)f2bfbits(a1[1] * invA);
        aA[6] = (short)f2bfbits(a1[2] * invA); aA[7] = (short)f2bfbits(a1[3] * invA);
        bf16x8 aB = aR;
        if (twoAgg) {
            f32x4 b0 = *(const f32x4*)(aggB + (size_t)arow * HH + k0);
            f32x4 b1 = *(const f32x4*)(aggB + (size_t)arow * HH + k0 + 4);
            aB[0] = (short)f2bfbits(b0[0] * invB); aB[1] = (short)f2bfbits(b0[1] * invB);
            aB[2] = (short)f2bfbits(b0[2] * invB); aB[3] = (short)f2bfbits(b0[3] * invB);
            aB[4] = (short)f2bfbits(b1[0] * invB); aB[5] = (short)f2bfbits(b1[1] * invB);
            aB[6] = (short)f2bfbits(b1[2] * invB); aB[7] = (short)f2bfbits(b1[3] * invB);
        }
        for (int ct = 0; ct < 8; ++ct) {
            const size_t wb = (size_t)((ct * 16 + m) * HH + k0);
            acc[ct] = __builtin_amdgcn_mfma_f32_16x16x32_bf16(
                aA, *(const bf16x8*)(WlA + wb), acc[ct], 0, 0, 0);
            acc[ct] = __builtin_amdgcn_mfma_f32_16x16x32_bf16(
                aR, *(const bf16x8*)(WrA + wb), acc[ct], 0, 0, 0);
            if (twoAgg) {
                acc[ct] = __builtin_amdgcn_mfma_f32_16x16x32_bf16(
                    aB, *(const bf16x8*)(WlB + wb), acc[ct], 0, 0, 0);
                acc[ct] = __builtin_amdgcn_mfma_f32_16x16x32_bf16(
                    aR, *(const bf16x8*)(WrB + wb), acc[ct], 0, 0, 0);
            }
        }
    }

    // -------- epilogue: bias -> (x0.5 if s) -> LN -> relu -> +residual --------
    const float scale = twoAgg ? 0.5f : 1.0f;
    float bias[8], gam[8], bet[8];
    for (int ct = 0; ct < 8; ++ct) {
        int j = ct * 16 + m;
        float bb = blA[j];
        if (twoAgg) bb += blB[j];
        bias[ct] = bb;
        gam[ct]  = g[j];
        bet[ct]  = bt[j];
    }
    float mu[4], rstd[4];
    for (int r = 0; r < 4; ++r) {
        float p = 0.f, p2 = 0.f;
        for (int ct = 0; ct < 8; ++ct) {
            float c = (acc[ct][r] + bias[ct]) * scale;
            acc[ct][r] = c;
            p += c; p2 += c * c;
        }
        // reduce across the 16-lane group (fixed q) holding one C row
        for (int off = 1; off < 16; off <<= 1) {
            p  += __shfl_xor(p,  off);
            p2 += __shfl_xor(p2, off);
        }
        float mean = p * (1.0f / 128.0f);
        float var  = p2 * (1.0f / 128.0f) - mean * mean;
        mu[r]   = mean;
        rstd[r] = rsqrtf(var + 1e-5f);
    }
    for (int r = 0; r < 4; ++r) {
        int i = row0 + q * 4 + r;
        if (i >= NN) continue;
        for (int ct = 0; ct < 8; ++ct) {
            int j = ct * 16 + m;
            float v = (acc[ct][r] - mu[r]) * rstd[r] * gam[ct] + bet[ct];
            v = fmaxf(v, 0.f);
            float res = XF32 ? ((const float*)X)[(size_t)i * HH + j]
                             : bfbits2f(((const unsigned short*)X)[(size_t)i * HH + j]);
            out[(size_t)i * HH + j] = f2bfbits(v + res);
        }
    }
}

// ---------------------------------------------------------------------------
// Final projection: out = X @ Wout^T + bout   (NN x 64), fp32 output
// ---------------------------------------------------------------------------
__global__ __launch_bounds__(256) void final_proj(
    const unsigned short* __restrict__ X, const unsigned short* __restrict__ W,
    const float* __restrict__ bias, float* __restrict__ out)
{
    const int lane = threadIdx.x & 63;
    const int wid  = threadIdx.x >> 6;
    const int m    = lane & 15;
    const int q    = lane >> 4;
    const int row0 = blockIdx.x * 64 + wid * 16;
    int arow = row0 + m;
    if (arow >= NN) arow = NN - 1;

    f32x4 acc[4];
    for (int ct = 0; ct < 4; ++ct) acc[ct] = (f32x4){0.f, 0.f, 0.f, 0.f};

    for (int ks = 0; ks < 4; ++ks) {
        const int k0 = ks * 32 + q * 8;
        bf16x8 aR = *(const bf16x8*)(X + (size_t)arow * HH + k0);
        for (int ct = 0; ct < 4; ++ct) {
            const size_t wb = (size_t)((ct * 16 + m) * HH + k0);
            acc[ct] = __builtin_amdgcn_mfma_f32_16x16x32_bf16(
                aR, *(const bf16x8*)(W + wb), acc[ct], 0, 0, 0);
        }
    }
    for (int r = 0; r < 4; ++r) {
        int i = row0 + q * 4 + r;
        if (i >= NN) continue;
        for (int ct = 0; ct < 4; ++ct) {
            int j = ct * 16 + m;
            out[(size_t)i * OUTC + j] = acc[ct][r] + bias[j];
        }
    }
}

// ---------------------------------------------------------------------------
extern "C" void kernel_launch(void* const* d_in, const int* in_sizes, int n_in,
                              void* d_out, int out_size, void* d_ws, size_t ws_size,
                              hipStream_t stream)
{
    const float* xs  = (const float*)d_in[0];
    const float* xo  = (const float*)d_in[1];
    const float* xf  = (const float*)d_in[2];
    const int* ei0 = (const int*)d_in[3];
    const int* ei1 = (const int*)d_in[4];
    const int* ei2 = (const int*)d_in[5];
    const int* ei3 = (const int*)d_in[6];
    const float* Wl1 = (const float*)d_in[7];
    const float* bl1 = (const float*)d_in[8];
    const float* Wr1 = (const float*)d_in[9];
    const float* Wl2 = (const float*)d_in[10];
    const float* bl2 = (const float*)d_in[11];
    const float* Wr2 = (const float*)d_in[12];
    const float* lng = (const float*)d_in[13];
    const float* lnb = (const float*)d_in[14];
    const float* Wou = (const float*)d_in[15];
    const float* bou = (const float*)d_in[16];
    float* out = (float*)d_out;

    // workspace layout (16B aligned): aggA|aggB|degA|degB|s1|o1|f1|weights(bf16)
    char* ws = (char*)d_ws;
    const size_t aggBytes = (size_t)NN * HH * 4;   // 51.2 MB
    const size_t degBytes = (size_t)NN * 4;        // 0.4 MB
    const size_t xBytes   = (size_t)NN * HH * 2;   // 25.6 MB (bf16)
    const int    WH       = HH * HH;               // 16384
    float* aggA = (float*)ws;                 ws += aggBytes;
    float* aggB = (float*)ws;                 ws += aggBytes;
    float* degA = (float*)ws;                 ws += degBytes;
    float* degB = (float*)ws;                 ws += degBytes;
    unsigned short* s1 = (unsigned short*)ws; ws += xBytes;
    unsigned short* o1 = (unsigned short*)ws; ws += xBytes;
    unsigned short* f1 = (unsigned short*)ws; ws += xBytes;
    unsigned short* Wl1b = (unsigned short*)ws; ws += (size_t)4 * WH * 2;
    unsigned short* Wr1b = (unsigned short*)ws; ws += (size_t)4 * WH * 2;
    unsigned short* Wl2b = (unsigned short*)ws; ws += (size_t)4 * WH * 2;
    unsigned short* Wr2b = (unsigned short*)ws; ws += (size_t)4 * WH * 2;
    unsigned short* Woub = (unsigned short*)ws; ws += (size_t)OUTC * HH * 2;
    unsigned short* s2 = o1;  // o1 is dead by the time s2 is written

    const int sgrid = (EE + 3) / 4;     // 1 wave per edge, 4 waves per block
    const int ggrid = (NN + 63) / 64;   // 64 rows per block

    // ---- pre-convert weights to bf16 (reused 100k x) ----
    cvt_f32_bf16<<<(4 * WH + 255) / 256, 256, 0, stream>>>(Wl1, Wl1b, 4 * WH);
    cvt_f32_bf16<<<(4 * WH + 255) / 256, 256, 0, stream>>>(Wr1, Wr1b, 4 * WH);
    cvt_f32_bf16<<<(4 * WH + 255) / 256, 256, 0, stream>>>(Wl2, Wl2b, 4 * WH);
    cvt_f32_bf16<<<(4 * WH + 255) / 256, 256, 0, stream>>>(Wr2, Wr2b, 4 * WH);
    cvt_f32_bf16<<<(OUTC * HH + 255) / 256, 256, 0, stream>>>(Wou, Woub, OUTC * HH);

    // ---- layer 1: edge type 0 (study->outcome) -> o1 ----
    hipMemsetAsync(aggA, 0, aggBytes, stream);
    hipMemsetAsync(degA, 0, degBytes, stream);
    scatter_edges<true><<<sgrid, 256, 0, stream>>>(ei0, xs, aggA, degA);
    sage_gemm<true><<<ggrid, 256, 0, stream>>>(aggA, degA, Wl1b + 0 * WH, bl1 + 0 * HH,
        nullptr, nullptr, nullptr, nullptr,
        xo, Wr1b + 0 * WH, nullptr, lng, lnb, o1, 0);

    // ---- layer 1: edge type 2 (study->facility) -> f1 ----
    hipMemsetAsync(aggA, 0, aggBytes, stream);
    hipMemsetAsync(degA, 0, degBytes, stream);
    scatter_edges<true><<<sgrid, 256, 0, stream>>>(ei2, xs, aggA, degA);
    sage_gemm<true><<<ggrid, 256, 0, stream>>>(aggA, degA, Wl1b + 2 * WH, bl1 + 2 * HH,
        nullptr, nullptr, nullptr, nullptr,
        xf, Wr1b + 2 * WH, nullptr, lng, lnb, f1, 0);

    // ---- layer 1: edge types 1,3 (outcome->study, facility->study) -> s1 ----
    hipMemsetAsync(aggA, 0, 2 * aggBytes, stream);   // aggA+aggB contiguous
    hipMemsetAsync(degA, 0, 2 * degBytes, stream);   // degA+degB contiguous
    scatter_edges<true><<<sgrid, 256, 0, stream>>>(ei1, xo, aggA, degA);
    scatter_edges<true><<<sgrid, 256, 0, stream>>>(ei3, xf, aggB, degB);
    sage_gemm<true><<<ggrid, 256, 0, stream>>>(aggA, degA, Wl1b + 1 * WH, bl1 + 1 * HH,
        aggB, degB, Wl1b + 3 * WH, bl1 + 3 * HH,
        xs, Wr1b + 1 * WH, Wr1b + 3 * WH, lng, lnb, s1, 1);

    // ---- layer 2: only the study output feeds the final projection ----
    hipMemsetAsync(aggA, 0, 2 * aggBytes, stream);
    hipMemsetAsync(degA, 0, 2 * degBytes, stream);
    scatter_edges<false><<<sgrid, 256, 0, stream>>>(ei1, o1, aggA, degA);
    scatter_edges<false><<<sgrid, 256, 0, stream>>>(ei3, f1, aggB, degB);
    sage_gemm<false><<<ggrid, 256, 0, stream>>>(aggA, degA, Wl2b + 1 * WH, bl2 + 1 * HH,
        aggB, degB, Wl2b + 3 * WH, bl2 + 3 * HH,
        s1, Wr2b + 1 * WH, Wr2b + 3 * WH, lng + HH, lnb + HH, s2, 1);

    // ---- final projection (fp32 out) ----
    final_proj<<<ggrid, 256, 0, stream>>>(s2, Woub, bou, out);
}

// Round 3
// 1293.848 us; speedup vs baseline: 2.9126x; 2.9126x over previous
//
#include <hip/hip_runtime.h>
#include <hip/hip_bf16.h>
#include <stdint.h>

#define NN   100000   // nodes per type
#define EE   600000   // edges per type
#define HH   128      // hidden
#define OUTC 64       // out channels

#define SCAN_N   (4 * NN)                       // 400000 counters (4 edge types)
#define CHUNK    1024
#define NCHUNK   ((SCAN_N + CHUNK - 1) / CHUNK) // 391

typedef __attribute__((ext_vector_type(8))) short bf16x8;   // 8 bf16 in 4 VGPRs
typedef __attribute__((ext_vector_type(4))) float f32x4;

__device__ __forceinline__ float bfbits2f(unsigned short b) {
    union { unsigned u; float f; } v; v.u = ((unsigned)b) << 16; return v.f;
}
__device__ __forceinline__ unsigned short f2bfbits(float f) {
    union { float f; unsigned u; } v; v.f = f;
    unsigned r = v.u + 0x7fffu + ((v.u >> 16) & 1u);   // RNE
    return (unsigned short)(r >> 16);
}

// ---------------------------------------------------------------------------
__global__ __launch_bounds__(256) void cvt_f32_bf16(
    const float* __restrict__ in, unsigned short* __restrict__ out, int n)
{
    int i = blockIdx.x * 256 + threadIdx.x;
    if (i < n) out[i] = f2bfbits(in[i]);
}

// ---------------------------------------------------------------------------
// CSR build: histogram over dst per edge type (4 types concatenated)
// ---------------------------------------------------------------------------
__global__ __launch_bounds__(256) void hist4(
    const int* __restrict__ ei0, const int* __restrict__ ei1,
    const int* __restrict__ ei2, const int* __restrict__ ei3,
    int* __restrict__ degAll)
{
    int gid = blockIdx.x * 256 + threadIdx.x;
    if (gid >= 4 * EE) return;
    int t = gid / EE, e = gid - t * EE;
    const int* ei = (t == 0) ? ei0 : (t == 1) ? ei1 : (t == 2) ? ei2 : ei3;
    atomicAdd(&degAll[t * NN + ei[EE + e]], 1);
}

// exclusive scan over SCAN_N ints, 3-kernel; also initializes the fill cursor
__global__ __launch_bounds__(256) void scan_partial(
    const int* __restrict__ in, int* __restrict__ chunkSums)
{
    __shared__ int sm[256];
    int tid = threadIdx.x;
    int base = blockIdx.x * CHUNK + tid * 4;
    int s = 0;
    for (int k = 0; k < 4; ++k) if (base + k < SCAN_N) s += in[base + k];
    sm[tid] = s; __syncthreads();
    for (int off = 128; off > 0; off >>= 1) {
        if (tid < off) sm[tid] += sm[tid + off];
        __syncthreads();
    }
    if (tid == 0) chunkSums[blockIdx.x] = sm[0];
}

__global__ __launch_bounds__(256) void scan_chunks(int* __restrict__ chunkSums)
{
    __shared__ int sm[NCHUNK];
    for (int i = threadIdx.x; i < NCHUNK; i += 256) sm[i] = chunkSums[i];
    __syncthreads();
    if (threadIdx.x == 0) {
        int run = 0;
        for (int i = 0; i < NCHUNK; ++i) { int v = sm[i]; sm[i] = run; run += v; }
    }
    __syncthreads();
    for (int i = threadIdx.x; i < NCHUNK; i += 256) chunkSums[i] = sm[i];
}

__global__ __launch_bounds__(256) void scan_final(
    const int* __restrict__ degAll, const int* __restrict__ chunkSums,
    int* __restrict__ offAll, int* __restrict__ curAll)
{
    __shared__ int sm[256];
    int tid = threadIdx.x;
    int base = blockIdx.x * CHUNK + tid * 4;
    int v[4]; int s = 0;
    for (int k = 0; k < 4; ++k) {
        v[k] = (base + k < SCAN_N) ? degAll[base + k] : 0;
        s += v[k];
    }
    sm[tid] = s; __syncthreads();
    for (int off = 1; off < 256; off <<= 1) {
        int t_ = (tid >= off) ? sm[tid - off] : 0;
        __syncthreads();
        sm[tid] += t_;
        __syncthreads();
    }
    int run = chunkSums[blockIdx.x] + sm[tid] - s;   // exclusive base
    for (int k = 0; k < 4; ++k) {
        if (base + k < SCAN_N) { offAll[base + k] = run; curAll[base + k] = run; run += v[k]; }
    }
    if (blockIdx.x == 0 && tid == 0) offAll[SCAN_N] = 4 * EE;
}

__global__ __launch_bounds__(256) void fill4(
    const int* __restrict__ ei0, const int* __restrict__ ei1,
    const int* __restrict__ ei2, const int* __restrict__ ei3,
    int* __restrict__ curAll, int* __restrict__ colAll)
{
    int gid = blockIdx.x * 256 + threadIdx.x;
    if (gid >= 4 * EE) return;
    int t = gid / EE, e = gid - t * EE;
    const int* ei = (t == 0) ? ei0 : (t == 1) ? ei1 : (t == 2) ? ei2 : ei3;
    int src = ei[e];
    int dst = ei[EE + e];
    int pos = atomicAdd(&curAll[t * NN + dst], 1);
    colAll[pos] = src;
}

// ---------------------------------------------------------------------------
// Gather-mean: one wave per dst row; lane covers feats [2*lane, 2*lane+1].
// Register accumulation, single normalized bf16 row write. No atomics.
// ---------------------------------------------------------------------------
template<bool SRCF32>
__global__ __launch_bounds__(256) void gather_mean(
    const int* __restrict__ off,     // offAll + t*NN (NN+1 valid entries)
    const int* __restrict__ colAll,  // global slot ids
    const void* __restrict__ xsrc_,  // [NN*HH] fp32 or bf16
    unsigned* __restrict__ out)      // [NN*HH/2] packed bf16x2, normalized
{
    int w    = (blockIdx.x * 256 + threadIdx.x) >> 6;
    int lane = threadIdx.x & 63;
    if (w >= NN) return;
    int o0 = off[w], o1 = off[w + 1];
    float ax = 0.f, ay = 0.f;
    for (int j = o0; j < o1; ++j) {
        int src = colAll[j];
        if (SRCF32) {
            float2 v = ((const float2*)((const float*)xsrc_ + (size_t)src * HH))[lane];
            ax += v.x; ay += v.y;
        } else {
            unsigned v = ((const unsigned*)((const unsigned short*)xsrc_ + (size_t)src * HH))[lane];
            ax += bfbits2f((unsigned short)(v & 0xffffu));
            ay += bfbits2f((unsigned short)(v >> 16));
        }
    }
    float inv = 1.0f / fmaxf((float)(o1 - o0), 1.0f);
    unsigned lo = f2bfbits(ax * inv);
    unsigned hi = f2bfbits(ay * inv);
    out[(size_t)w * 64 + lane] = (hi << 16) | lo;
}

// ---------------------------------------------------------------------------
// SAGE GEMM + fused LN/ReLU/residual epilogue.
//   C = agg16A @ WlA^T + X @ WrA^T + blA   (+ agg16B @ WlB^T + X @ WrB^T + blB)
//   out = relu(LN(scale*C; g,b)) + X       (scale=0.5 when twoAgg)
// One wave = 16 rows x 128 cols; block = 4 waves. agg16* pre-normalized bf16.
// ---------------------------------------------------------------------------
template<bool XF32>
__global__ __launch_bounds__(256) void sage_gemm(
    const unsigned short* __restrict__ agg16A,
    const unsigned short* __restrict__ WlA, const float* __restrict__ blA,
    const unsigned short* __restrict__ agg16B,
    const unsigned short* __restrict__ WlB, const float* __restrict__ blB,
    const void* __restrict__ X,       // root features = residual source
    const unsigned short* __restrict__ WrA, const unsigned short* __restrict__ WrB,
    const float* __restrict__ g, const float* __restrict__ bt,
    unsigned short* __restrict__ out, int twoAgg)
{
    const int lane = threadIdx.x & 63;
    const int wid  = threadIdx.x >> 6;
    const int m    = lane & 15;
    const int q    = lane >> 4;
    const int row0 = blockIdx.x * 64 + wid * 16;

    int arow = row0 + m;
    if (arow >= NN) arow = NN - 1;          // clamp loads; stores guarded

    f32x4 acc[8];
    for (int ct = 0; ct < 8; ++ct) acc[ct] = (f32x4){0.f, 0.f, 0.f, 0.f};

    for (int ks = 0; ks < 4; ++ks) {
        const int k0 = ks * 32 + q * 8;
        bf16x8 aR;
        if (XF32) {
            f32x4 r0 = *(const f32x4*)((const float*)X + (size_t)arow * HH + k0);
            f32x4 r1 = *(const f32x4*)((const float*)X + (size_t)arow * HH + k0 + 4);
            aR[0] = (short)f2bfbits(r0[0]); aR[1] = (short)f2bfbits(r0[1]);
            aR[2] = (short)f2bfbits(r0[2]); aR[3] = (short)f2bfbits(r0[3]);
            aR[4] = (short)f2bfbits(r1[0]); aR[5] = (short)f2bfbits(r1[1]);
            aR[6] = (short)f2bfbits(r1[2]); aR[7] = (short)f2bfbits(r1[3]);
        } else {
            aR = *(const bf16x8*)((const unsigned short*)X + (size_t)arow * HH + k0);
        }
        bf16x8 aA = *(const bf16x8*)(agg16A + (size_t)arow * HH + k0);
        bf16x8 aB = aR;
        if (twoAgg) aB = *(const bf16x8*)(agg16B + (size_t)arow * HH + k0);
        for (int ct = 0; ct < 8; ++ct) {
            const size_t wb = (size_t)((ct * 16 + m) * HH + k0);
            acc[ct] = __builtin_amdgcn_mfma_f32_16x16x32_bf16(
                aA, *(const bf16x8*)(WlA + wb), acc[ct], 0, 0, 0);
            acc[ct] = __builtin_amdgcn_mfma_f32_16x16x32_bf16(
                aR, *(const bf16x8*)(WrA + wb), acc[ct], 0, 0, 0);
            if (twoAgg) {
                acc[ct] = __builtin_amdgcn_mfma_f32_16x16x32_bf16(
                    aB, *(const bf16x8*)(WlB + wb), acc[ct], 0, 0, 0);
                acc[ct] = __builtin_amdgcn_mfma_f32_16x16x32_bf16(
                    aR, *(const bf16x8*)(WrB + wb), acc[ct], 0, 0, 0);
            }
        }
    }

    // -------- epilogue: bias -> (x0.5 if s) -> LN -> relu -> +residual --------
    const float scale = twoAgg ? 0.5f : 1.0f;
    float bias[8], gam[8], bet[8];
    for (int ct = 0; ct < 8; ++ct) {
        int j = ct * 16 + m;
        float bb = blA[j];
        if (twoAgg) bb += blB[j];
        bias[ct] = bb;
        gam[ct]  = g[j];
        bet[ct]  = bt[j];
    }
    float mu[4], rstd[4];
    for (int r = 0; r < 4; ++r) {
        float p = 0.f, p2 = 0.f;
        for (int ct = 0; ct < 8; ++ct) {
            float c = (acc[ct][r] + bias[ct]) * scale;
            acc[ct][r] = c;
            p += c; p2 += c * c;
        }
        for (int off = 1; off < 16; off <<= 1) {
            p  += __shfl_xor(p,  off);
            p2 += __shfl_xor(p2, off);
        }
        float mean = p * (1.0f / 128.0f);
        float var  = p2 * (1.0f / 128.0f) - mean * mean;
        mu[r]   = mean;
        rstd[r] = rsqrtf(var + 1e-5f);
    }
    for (int r = 0; r < 4; ++r) {
        int i = row0 + q * 4 + r;
        if (i >= NN) continue;
        for (int ct = 0; ct < 8; ++ct) {
            int j = ct * 16 + m;
            float v = (acc[ct][r] - mu[r]) * rstd[r] * gam[ct] + bet[ct];
            v = fmaxf(v, 0.f);
            float res = XF32 ? ((const float*)X)[(size_t)i * HH + j]
                             : bfbits2f(((const unsigned short*)X)[(size_t)i * HH + j]);
            out[(size_t)i * HH + j] = f2bfbits(v + res);
        }
    }
}

// ---------------------------------------------------------------------------
// Final projection: out = X @ Wout^T + bout   (NN x 64), fp32 output
// ---------------------------------------------------------------------------
__global__ __launch_bounds__(256) void final_proj(
    const unsigned short* __restrict__ X, const unsigned short* __restrict__ W,
    const float* __restrict__ bias, float* __restrict__ out)
{
    const int lane = threadIdx.x & 63;
    const int wid  = threadIdx.x >> 6;
    const int m    = lane & 15;
    const int q    = lane >> 4;
    const int row0 = blockIdx.x * 64 + wid * 16;
    int arow = row0 + m;
    if (arow >= NN) arow = NN - 1;

    f32x4 acc[4];
    for (int ct = 0; ct < 4; ++ct) acc[ct] = (f32x4){0.f, 0.f, 0.f, 0.f};

    for (int ks = 0; ks < 4; ++ks) {
        const int k0 = ks * 32 + q * 8;
        bf16x8 aR = *(const bf16x8*)(X + (size_t)arow * HH + k0);
        for (int ct = 0; ct < 4; ++ct) {
            const size_t wb = (size_t)((ct * 16 + m) * HH + k0);
            acc[ct] = __builtin_amdgcn_mfma_f32_16x16x32_bf16(
                aR, *(const bf16x8*)(W + wb), acc[ct], 0, 0, 0);
        }
    }
    for (int r = 0; r < 4; ++r) {
        int i = row0 + q * 4 + r;
        if (i >= NN) continue;
        for (int ct = 0; ct < 4; ++ct) {
            int j = ct * 16 + m;
            out[(size_t)i * OUTC + j] = acc[ct][r] + bias[j];
        }
    }
}

// ---------------------------------------------------------------------------
extern "C" void kernel_launch(void* const* d_in, const int* in_sizes, int n_in,
                              void* d_out, int out_size, void* d_ws, size_t ws_size,
                              hipStream_t stream)
{
    const float* xs  = (const float*)d_in[0];
    const float* xo  = (const float*)d_in[1];
    const float* xf  = (const float*)d_in[2];
    const int* ei0 = (const int*)d_in[3];
    const int* ei1 = (const int*)d_in[4];
    const int* ei2 = (const int*)d_in[5];
    const int* ei3 = (const int*)d_in[6];
    const float* Wl1 = (const float*)d_in[7];
    const float* bl1 = (const float*)d_in[8];
    const float* Wr1 = (const float*)d_in[9];
    const float* Wl2 = (const float*)d_in[10];
    const float* bl2 = (const float*)d_in[11];
    const float* Wr2 = (const float*)d_in[12];
    const float* lng = (const float*)d_in[13];
    const float* lnb = (const float*)d_in[14];
    const float* Wou = (const float*)d_in[15];
    const float* bou = (const float*)d_in[16];
    float* out = (float*)d_out;

    // workspace layout (16B aligned)
    char* ws = (char*)d_ws;
    const size_t xBytes = (size_t)NN * HH * 2;     // 25.6 MB (bf16)
    const int    WH     = HH * HH;                 // 16384
    unsigned short* aggA16 = (unsigned short*)ws; ws += xBytes;
    unsigned short* aggB16 = (unsigned short*)ws; ws += xBytes;
    unsigned short* s1 = (unsigned short*)ws;     ws += xBytes;
    unsigned short* o1 = (unsigned short*)ws;     ws += xBytes;
    unsigned short* f1 = (unsigned short*)ws;     ws += xBytes;
    int* degAll    = (int*)ws; ws += (size_t)SCAN_N * 4;
    int* offAll    = (int*)ws; ws += (size_t)(SCAN_N + 4) * 4;
    int* curAll    = (int*)ws; ws += (size_t)SCAN_N * 4;
    int* colAll    = (int*)ws; ws += (size_t)4 * EE * 4;
    int* chunkSums = (int*)ws; ws += (size_t)NCHUNK * 4;
    unsigned short* Wl1b = (unsigned short*)ws; ws += (size_t)4 * WH * 2;
    unsigned short* Wr1b = (unsigned short*)ws; ws += (size_t)4 * WH * 2;
    unsigned short* Wl2b = (unsigned short*)ws; ws += (size_t)4 * WH * 2;
    unsigned short* Wr2b = (unsigned short*)ws; ws += (size_t)4 * WH * 2;
    unsigned short* Woub = (unsigned short*)ws; ws += (size_t)OUTC * HH * 2;
    unsigned short* s2 = o1;   // o1 dead once layer-2 gathers are done

    const int egrid = (4 * EE + 255) / 256;   // hist / fill
    const int ngrid = (NN * 64 + 255) / 256;  // gather: 1 wave per node
    const int ggrid = (NN + 63) / 64;         // gemm: 64 rows per block

    // ---- weights -> bf16 (reused 100k x) ----
    cvt_f32_bf16<<<(4 * WH + 255) / 256, 256, 0, stream>>>(Wl1, Wl1b, 4 * WH);
    cvt_f32_bf16<<<(4 * WH + 255) / 256, 256, 0, stream>>>(Wr1, Wr1b, 4 * WH);
    cvt_f32_bf16<<<(4 * WH + 255) / 256, 256, 0, stream>>>(Wl2, Wl2b, 4 * WH);
    cvt_f32_bf16<<<(4 * WH + 255) / 256, 256, 0, stream>>>(Wr2, Wr2b, 4 * WH);
    cvt_f32_bf16<<<(OUTC * HH + 255) / 256, 256, 0, stream>>>(Wou, Woub, OUTC * HH);

    // ---- CSR build for all 4 edge types ----
    hipMemsetAsync(degAll, 0, (size_t)SCAN_N * 4, stream);
    hist4<<<egrid, 256, 0, stream>>>(ei0, ei1, ei2, ei3, degAll);
    scan_partial<<<NCHUNK, 256, 0, stream>>>(degAll, chunkSums);
    scan_chunks<<<1, 256, 0, stream>>>(chunkSums);
    scan_final<<<NCHUNK, 256, 0, stream>>>(degAll, chunkSums, offAll, curAll);
    fill4<<<egrid, 256, 0, stream>>>(ei0, ei1, ei2, ei3, curAll, colAll);

    // ---- layer 1: type 0 (study->outcome) -> o1 ----
    gather_mean<true><<<ngrid, 256, 0, stream>>>(offAll + 0 * NN, colAll, xs, (unsigned*)aggA16);
    sage_gemm<true><<<ggrid, 256, 0, stream>>>(aggA16, Wl1b + 0 * WH, bl1 + 0 * HH,
        nullptr, nullptr, nullptr,
        xo, Wr1b + 0 * WH, nullptr, lng, lnb, o1, 0);

    // ---- layer 1: type 2 (study->facility) -> f1 ----
    gather_mean<true><<<ngrid, 256, 0, stream>>>(offAll + 2 * NN, colAll, xs, (unsigned*)aggA16);
    sage_gemm<true><<<ggrid, 256, 0, stream>>>(aggA16, Wl1b + 2 * WH, bl1 + 2 * HH,
        nullptr, nullptr, nullptr,
        xf, Wr1b + 2 * WH, nullptr, lng, lnb, f1, 0);

    // ---- layer 1: types 1,3 (outcome->study, facility->study) -> s1 ----
    gather_mean<true><<<ngrid, 256, 0, stream>>>(offAll + 1 * NN, colAll, xo, (unsigned*)aggA16);
    gather_mean<true><<<ngrid, 256, 0, stream>>>(offAll + 3 * NN, colAll, xf, (unsigned*)aggB16);
    sage_gemm<true><<<ggrid, 256, 0, stream>>>(aggA16, Wl1b + 1 * WH, bl1 + 1 * HH,
        aggB16, Wl1b + 3 * WH, bl1 + 3 * HH,
        xs, Wr1b + 1 * WH, Wr1b + 3 * WH, lng, lnb, s1, 1);

    // ---- layer 2: only the study output feeds the final projection ----
    gather_mean<false><<<ngrid, 256, 0, stream>>>(offAll + 1 * NN, colAll, o1, (unsigned*)aggA16);
    gather_mean<false><<<ngrid, 256, 0, stream>>>(offAll + 3 * NN, colAll, f1, (unsigned*)aggB16);
    sage_gemm<false><<<ggrid, 256, 0, stream>>>(aggA16, Wl2b + 1 * WH, bl2 + 1 * HH,
        aggB16, Wl2b + 3 * WH, bl2 + 3 * HH,
        s1, Wr2b + 1 * WH, Wr2b + 3 * WH, lng + HH, lnb + HH, s2, 1);

    // ---- final projection (fp32 out) ----
    final_proj<<<ggrid, 256, 0, stream>>>(s2, Woub, bou, out);
}

// Round 4
// 1169.557 us; speedup vs baseline: 3.2222x; 1.1063x over previous
//
#include <hip/hip_runtime.h>
#include <hip/hip_bf16.h>
#include <stdint.h>

#define NN   100000   // nodes per type
#define EE   600000   // edges per type
#define HH   128      // hidden
#define OUTC 64       // out channels

typedef __attribute__((ext_vector_type(8))) short bf16x8;   // 8 bf16 in 4 VGPRs
typedef __attribute__((ext_vector_type(4))) float f32x4;

__device__ __forceinline__ float bfbits2f(unsigned short b) {
    union { unsigned u; float f; } v; v.u = ((unsigned)b) << 16; return v.f;
}
__device__ __forceinline__ unsigned short f2bfbits(float f) {
    union { float f; unsigned u; } v; v.f = f;
    unsigned r = v.u + 0x7fffu + ((v.u >> 16) & 1u);   // RNE
    return (unsigned short)(r >> 16);
}

// ---------------------------------------------------------------------------
__global__ __launch_bounds__(256) void cvt_f32_bf16(
    const float* __restrict__ in, unsigned short* __restrict__ out, int n)
{
    int i = blockIdx.x * 256 + threadIdx.x;
    if (i < n) out[i] = f2bfbits(in[i]);
}

// ---------------------------------------------------------------------------
// Linked-list adjacency build, all 4 edge types in one pass.
//   node[t*EE+e] = (src, prev_head);  head[t*NN+dst] = t*EE+e  (atomicExch)
// node writes are coalesced (indexed by edge id); only head is scattered,
// and it is a 1.6 MB L2-resident int region.
// ---------------------------------------------------------------------------
__global__ __launch_bounds__(256) void build_ll(
    const int* __restrict__ ei0, const int* __restrict__ ei1,
    const int* __restrict__ ei2, const int* __restrict__ ei3,
    int* __restrict__ head,      // [4*NN], pre-init to -1
    int2* __restrict__ node)     // [4*EE]
{
    int gid = blockIdx.x * 256 + threadIdx.x;
    if (gid >= 4 * EE) return;
    int t = gid / EE, e = gid - t * EE;
    const int* ei = (t == 0) ? ei0 : (t == 1) ? ei1 : (t == 2) ? ei2 : ei3;
    int src = ei[e];
    int dst = ei[EE + e];
    int prev = atomicExch(&head[t * NN + dst], gid);
    node[gid] = make_int2(src, prev);
}

// ---------------------------------------------------------------------------
// Gather-mean via linked-list traversal: one wave per dst row; lane covers
// feats [2*lane, 2*lane+1]. Wave-uniform chase, register accumulation,
// single normalized bf16 row write. Degree counted on the fly.
// ---------------------------------------------------------------------------
template<bool SRCF32>
__global__ __launch_bounds__(256) void gather_ll(
    const int* __restrict__ head,    // head + t*NN
    const int2* __restrict__ node,   // global edge-slot array
    const void* __restrict__ xsrc_,  // [NN*HH] fp32 or bf16
    unsigned* __restrict__ out)      // [NN*HH/2] packed bf16x2, normalized
{
    int w    = (blockIdx.x * 256 + threadIdx.x) >> 6;
    int lane = threadIdx.x & 63;
    if (w >= NN) return;
    int e = head[w];
    float ax = 0.f, ay = 0.f;
    int cnt = 0;
    while (e >= 0) {
        int2 n = node[e];          // (src, next) — one dependent 8B load/hop
        if (SRCF32) {
            float2 v = ((const float2*)((const float*)xsrc_ + (size_t)n.x * HH))[lane];
            ax += v.x; ay += v.y;
        } else {
            unsigned v = ((const unsigned*)((const unsigned short*)xsrc_ + (size_t)n.x * HH))[lane];
            ax += bfbits2f((unsigned short)(v & 0xffffu));
            ay += bfbits2f((unsigned short)(v >> 16));
        }
        ++cnt;
        e = n.y;
    }
    float inv = 1.0f / fmaxf((float)cnt, 1.0f);
    unsigned lo = f2bfbits(ax * inv);
    unsigned hi = f2bfbits(ay * inv);
    out[(size_t)w * 64 + lane] = (hi << 16) | lo;
}

// ---------------------------------------------------------------------------
// SAGE GEMM + fused LN/ReLU/residual epilogue.
//   C = agg16A @ WlA^T + X @ WrA^T + blA   (+ agg16B @ WlB^T + X @ WrB^T + blB)
//   out = relu(LN(scale*C; g,b)) + X       (scale=0.5 when twoAgg)
// One wave = 16 rows x 128 cols; block = 4 waves. agg16* pre-normalized bf16.
// ---------------------------------------------------------------------------
template<bool XF32>
__global__ __launch_bounds__(256) void sage_gemm(
    const unsigned short* __restrict__ agg16A,
    const unsigned short* __restrict__ WlA, const float* __restrict__ blA,
    const unsigned short* __restrict__ agg16B,
    const unsigned short* __restrict__ WlB, const float* __restrict__ blB,
    const void* __restrict__ X,       // root features = residual source
    const unsigned short* __restrict__ WrA, const unsigned short* __restrict__ WrB,
    const float* __restrict__ g, const float* __restrict__ bt,
    unsigned short* __restrict__ out, int twoAgg)
{
    const int lane = threadIdx.x & 63;
    const int wid  = threadIdx.x >> 6;
    const int m    = lane & 15;
    const int q    = lane >> 4;
    const int row0 = blockIdx.x * 64 + wid * 16;

    int arow = row0 + m;
    if (arow >= NN) arow = NN - 1;          // clamp loads; stores guarded

    f32x4 acc[8];
    for (int ct = 0; ct < 8; ++ct) acc[ct] = (f32x4){0.f, 0.f, 0.f, 0.f};

    for (int ks = 0; ks < 4; ++ks) {
        const int k0 = ks * 32 + q * 8;
        bf16x8 aR;
        if (XF32) {
            f32x4 r0 = *(const f32x4*)((const float*)X + (size_t)arow * HH + k0);
            f32x4 r1 = *(const f32x4*)((const float*)X + (size_t)arow * HH + k0 + 4);
            aR[0] = (short)f2bfbits(r0[0]); aR[1] = (short)f2bfbits(r0[1]);
            aR[2] = (short)f2bfbits(r0[2]); aR[3] = (short)f2bfbits(r0[3]);
            aR[4] = (short)f2bfbits(r1[0]); aR[5] = (short)f2bfbits(r1[1]);
            aR[6] = (short)f2bfbits(r1[2]); aR[7] = (short)f2bfbits(r1[3]);
        } else {
            aR = *(const bf16x8*)((const unsigned short*)X + (size_t)arow * HH + k0);
        }
        bf16x8 aA = *(const bf16x8*)(agg16A + (size_t)arow * HH + k0);
        bf16x8 aB = aR;
        if (twoAgg) aB = *(const bf16x8*)(agg16B + (size_t)arow * HH + k0);
        for (int ct = 0; ct < 8; ++ct) {
            const size_t wb = (size_t)((ct * 16 + m) * HH + k0);
            acc[ct] = __builtin_amdgcn_mfma_f32_16x16x32_bf16(
                aA, *(const bf16x8*)(WlA + wb), acc[ct], 0, 0, 0);
            acc[ct] = __builtin_amdgcn_mfma_f32_16x16x32_bf16(
                aR, *(const bf16x8*)(WrA + wb), acc[ct], 0, 0, 0);
            if (twoAgg) {
                acc[ct] = __builtin_amdgcn_mfma_f32_16x16x32_bf16(
                    aB, *(const bf16x8*)(WlB + wb), acc[ct], 0, 0, 0);
                acc[ct] = __builtin_amdgcn_mfma_f32_16x16x32_bf16(
                    aR, *(const bf16x8*)(WrB + wb), acc[ct], 0, 0, 0);
            }
        }
    }

    // -------- epilogue: bias -> (x0.5 if s) -> LN -> relu -> +residual --------
    const float scale = twoAgg ? 0.5f : 1.0f;
    float bias[8], gam[8], bet[8];
    for (int ct = 0; ct < 8; ++ct) {
        int j = ct * 16 + m;
        float bb = blA[j];
        if (twoAgg) bb += blB[j];
        bias[ct] = bb;
        gam[ct]  = g[j];
        bet[ct]  = bt[j];
    }
    float mu[4], rstd[4];
    for (int r = 0; r < 4; ++r) {
        float p = 0.f, p2 = 0.f;
        for (int ct = 0; ct < 8; ++ct) {
            float c = (acc[ct][r] + bias[ct]) * scale;
            acc[ct][r] = c;
            p += c; p2 += c * c;
        }
        for (int off = 1; off < 16; off <<= 1) {
            p  += __shfl_xor(p,  off);
            p2 += __shfl_xor(p2, off);
        }
        float mean = p * (1.0f / 128.0f);
        float var  = p2 * (1.0f / 128.0f) - mean * mean;
        mu[r]   = mean;
        rstd[r] = rsqrtf(var + 1e-5f);
    }
    for (int r = 0; r < 4; ++r) {
        int i = row0 + q * 4 + r;
        if (i >= NN) continue;
        for (int ct = 0; ct < 8; ++ct) {
            int j = ct * 16 + m;
            float v = (acc[ct][r] - mu[r]) * rstd[r] * gam[ct] + bet[ct];
            v = fmaxf(v, 0.f);
            float res = XF32 ? ((const float*)X)[(size_t)i * HH + j]
                             : bfbits2f(((const unsigned short*)X)[(size_t)i * HH + j]);
            out[(size_t)i * HH + j] = f2bfbits(v + res);
        }
    }
}

// ---------------------------------------------------------------------------
// Final projection: out = X @ Wout^T + bout   (NN x 64), fp32 output
// ---------------------------------------------------------------------------
__global__ __launch_bounds__(256) void final_proj(
    const unsigned short* __restrict__ X, const unsigned short* __restrict__ W,
    const float* __restrict__ bias, float* __restrict__ out)
{
    const int lane = threadIdx.x & 63;
    const int wid  = threadIdx.x >> 6;
    const int m    = lane & 15;
    const int q    = lane >> 4;
    const int row0 = blockIdx.x * 64 + wid * 16;
    int arow = row0 + m;
    if (arow >= NN) arow = NN - 1;

    f32x4 acc[4];
    for (int ct = 0; ct < 4; ++ct) acc[ct] = (f32x4){0.f, 0.f, 0.f, 0.f};

    for (int ks = 0; ks < 4; ++ks) {
        const int k0 = ks * 32 + q * 8;
        bf16x8 aR = *(const bf16x8*)(X + (size_t)arow * HH + k0);
        for (int ct = 0; ct < 4; ++ct) {
            const size_t wb = (size_t)((ct * 16 + m) * HH + k0);
            acc[ct] = __builtin_amdgcn_mfma_f32_16x16x32_bf16(
                aR, *(const bf16x8*)(W + wb), acc[ct], 0, 0, 0);
        }
    }
    for (int r = 0; r < 4; ++r) {
        int i = row0 + q * 4 + r;
        if (i >= NN) continue;
        for (int ct = 0; ct < 4; ++ct) {
            int j = ct * 16 + m;
            out[(size_t)i * OUTC + j] = acc[ct][r] + bias[j];
        }
    }
}

// ---------------------------------------------------------------------------
extern "C" void kernel_launch(void* const* d_in, const int* in_sizes, int n_in,
                              void* d_out, int out_size, void* d_ws, size_t ws_size,
                              hipStream_t stream)
{
    const float* xs  = (const float*)d_in[0];
    const float* xo  = (const float*)d_in[1];
    const float* xf  = (const float*)d_in[2];
    const int* ei0 = (const int*)d_in[3];
    const int* ei1 = (const int*)d_in[4];
    const int* ei2 = (const int*)d_in[5];
    const int* ei3 = (const int*)d_in[6];
    const float* Wl1 = (const float*)d_in[7];
    const float* bl1 = (const float*)d_in[8];
    const float* Wr1 = (const float*)d_in[9];
    const float* Wl2 = (const float*)d_in[10];
    const float* bl2 = (const float*)d_in[11];
    const float* Wr2 = (const float*)d_in[12];
    const float* lng = (const float*)d_in[13];
    const float* lnb = (const float*)d_in[14];
    const float* Wou = (const float*)d_in[15];
    const float* bou = (const float*)d_in[16];
    float* out = (float*)d_out;

    // workspace layout (16B aligned)
    char* ws = (char*)d_ws;
    const size_t xBytes = (size_t)NN * HH * 2;     // 25.6 MB (bf16)
    const int    WH     = HH * HH;                 // 16384
    unsigned short* aggA16 = (unsigned short*)ws; ws += xBytes;
    unsigned short* aggB16 = (unsigned short*)ws; ws += xBytes;
    unsigned short* s1 = (unsigned short*)ws;     ws += xBytes;
    unsigned short* o1 = (unsigned short*)ws;     ws += xBytes;
    unsigned short* f1 = (unsigned short*)ws;     ws += xBytes;
    int*  head = (int*)ws;  ws += (size_t)4 * NN * 4;   // 1.6 MB
    int2* node = (int2*)ws; ws += (size_t)4 * EE * 8;   // 19.2 MB
    unsigned short* Wl1b = (unsigned short*)ws; ws += (size_t)4 * WH * 2;
    unsigned short* Wr1b = (unsigned short*)ws; ws += (size_t)4 * WH * 2;
    unsigned short* Wl2b = (unsigned short*)ws; ws += (size_t)4 * WH * 2;
    unsigned short* Wr2b = (unsigned short*)ws; ws += (size_t)4 * WH * 2;
    unsigned short* Woub = (unsigned short*)ws; ws += (size_t)OUTC * HH * 2;
    unsigned short* s2 = o1;   // o1 dead once layer-2 gathers are done

    const int egrid = (4 * EE + 255) / 256;   // build
    const int ngrid = (NN * 64 + 255) / 256;  // gather: 1 wave per node
    const int ggrid = (NN + 63) / 64;         // gemm: 64 rows per block

    // ---- weights -> bf16 (reused 100k x) ----
    cvt_f32_bf16<<<(4 * WH + 255) / 256, 256, 0, stream>>>(Wl1, Wl1b, 4 * WH);
    cvt_f32_bf16<<<(4 * WH + 255) / 256, 256, 0, stream>>>(Wr1, Wr1b, 4 * WH);
    cvt_f32_bf16<<<(4 * WH + 255) / 256, 256, 0, stream>>>(Wl2, Wl2b, 4 * WH);
    cvt_f32_bf16<<<(4 * WH + 255) / 256, 256, 0, stream>>>(Wr2, Wr2b, 4 * WH);
    cvt_f32_bf16<<<(OUTC * HH + 255) / 256, 256, 0, stream>>>(Wou, Woub, OUTC * HH);

    // ---- adjacency build (all 4 edge types) ----
    hipMemsetAsync(head, 0xFF, (size_t)4 * NN * 4, stream);   // head = -1
    build_ll<<<egrid, 256, 0, stream>>>(ei0, ei1, ei2, ei3, head, node);

    // ---- layer 1: type 0 (study->outcome) -> o1 ----
    gather_ll<true><<<ngrid, 256, 0, stream>>>(head + 0 * NN, node, xs, (unsigned*)aggA16);
    sage_gemm<true><<<ggrid, 256, 0, stream>>>(aggA16, Wl1b + 0 * WH, bl1 + 0 * HH,
        nullptr, nullptr, nullptr,
        xo, Wr1b + 0 * WH, nullptr, lng, lnb, o1, 0);

    // ---- layer 1: type 2 (study->facility) -> f1 ----
    gather_ll<true><<<ngrid, 256, 0, stream>>>(head + 2 * NN, node, xs, (unsigned*)aggA16);
    sage_gemm<true><<<ggrid, 256, 0, stream>>>(aggA16, Wl1b + 2 * WH, bl1 + 2 * HH,
        nullptr, nullptr, nullptr,
        xf, Wr1b + 2 * WH, nullptr, lng, lnb, f1, 0);

    // ---- layer 1: types 1,3 (outcome->study, facility->study) -> s1 ----
    gather_ll<true><<<ngrid, 256, 0, stream>>>(head + 1 * NN, node, xo, (unsigned*)aggA16);
    gather_ll<true><<<ngrid, 256, 0, stream>>>(head + 3 * NN, node, xf, (unsigned*)aggB16);
    sage_gemm<true><<<ggrid, 256, 0, stream>>>(aggA16, Wl1b + 1 * WH, bl1 + 1 * HH,
        aggB16, Wl1b + 3 * WH, bl1 + 3 * HH,
        xs, Wr1b + 1 * WH, Wr1b + 3 * WH, lng, lnb, s1, 1);

    // ---- layer 2: only the study output feeds the final projection ----
    gather_ll<false><<<ngrid, 256, 0, stream>>>(head + 1 * NN, node, o1, (unsigned*)aggA16);
    gather_ll<false><<<ngrid, 256, 0, stream>>>(head + 3 * NN, node, f1, (unsigned*)aggB16);
    sage_gemm<false><<<ggrid, 256, 0, stream>>>(aggA16, Wl2b + 1 * WH, bl2 + 1 * HH,
        aggB16, Wl2b + 3 * WH, bl2 + 3 * HH,
        s1, Wr2b + 1 * WH, Wr2b + 3 * WH, lng + HH, lnb + HH, s2, 1);

    // ---- final projection (fp32 out) ----
    final_proj<<<ggrid, 256, 0, stream>>>(s2, Woub, bou, out);
}